// Round 7
// baseline (120.212 us; speedup 1.0000x reference)
//
#include <hip/hip_runtime.h>
#include <hip/hip_fp16.h>

// Problem constants (from reference)
#define SPP    16
#define SH     256
#define SW     256
#define HI     1024
#define WI     1024
#define CH     3
#define BATCH  4
#define NPLANE (BATCH * CH)   // 12 (b,c) planes
#define PXB    32             // packed bytes per pixel (12 fp16 = 24 B, pad to 32)

// tanh via v_exp_f32; |arg| <= ~1.2 here, abs error ~1e-6 (threshold 1.7e-2).
__device__ __forceinline__ float fast_tanh(float x) {
    const float e = __expf(2.0f * x);
    return (e - 1.0f) * __builtin_amdgcn_rcpf(e + 1.0f);
}

// ---- Pass 1: NCHW f32 -> per-pixel packed [12 x fp16, pad 32 B] -----------
// Thread per pixel: 12 coalesced plane reads, one 16 B + one 8 B store.
__global__ __launch_bounds__(256) void repack12(
    const float* __restrict__ img, char* __restrict__ dst)
{
    const int pix = blockIdx.x * 256 + threadIdx.x;   // 0 .. 2^20-1
    float v[NPLANE];
    #pragma unroll
    for (int p = 0; p < NPLANE; ++p)
        v[p] = img[(size_t)p * (HI * WI) + pix];
    union { __half2 h[6]; struct { uint4 a; uint2 b; } u; } o;
    #pragma unroll
    for (int i = 0; i < 6; ++i)
        o.h[i] = __floats2half2_rn(v[2 * i], v[2 * i + 1]);
    char* d = dst + (size_t)pix * PXB;
    *(uint4*)d        = o.u.a;   // ch 0-7
    *(uint2*)(d + 16) = o.u.b;   // ch 8-11 (bytes 24-31 left as pad, never read)
}

// ---- Pass 2: gather from packed image -------------------------------------
// Thread = (sensor px, spp quarter): 4 samples each, geometry computed once
// per sample and shared by all 12 (b,c) outputs. Wave = 16 px x 4 quarters.
// Per sample: 2 rows x 2 px x (dwordx4 + dwordx2) = 8 aligned gathers carry
// ALL 12 plane values. Accumulate with packed fp16 FMA (6 half2 accs).
// Quarters reduced by __shfl_xor over lane bits 4,5. No LDS, no barriers.
//
// Border algebra: xb = min(floor(gx), W-2), fx = gx - xb (reaches 1.0 at the
// border) — identical to the reference's clamp.
__global__ __launch_bounds__(256) void foveated_pk(
    const char* __restrict__ pk,
    const float* __restrict__ t_ptr,
    const float* __restrict__ jitter,
    float* __restrict__ out)
{
    // 1024 logical blocks of 64 sensor px; XCD slab swizzle (128 blocks =
    // 32 sensor rows per XCD -> ~1 MB packed slab, L2-resident).
    const int L   = (blockIdx.x & 7) * 128 + (blockIdx.x >> 3);
    const int th  = threadIdx.x;
    const int lpx = th & 15;          // px low bits (lane bits 0-3)
    const int q   = (th >> 4) & 3;    // spp quarter (lane bits 4-5)
    const int wv  = th >> 6;          // wave in block
    const int pix = L * 64 + wv * 16 + lpx;
    const int sx  = pix & (SW - 1);
    const int sy  = pix >> 8;

    const float step  = 2.0f / 256.0f;
    const float tt    = t_ptr[0];
    const float inv_s = __builtin_amdgcn_rcpf(fast_tanh(tt));
    const float px    = -1.0f + sx * step;
    const float py    = -1.0f + sy * step;

    const float2* __restrict__ jit2 = (const float2*)jitter;

    __half2 acc[6];
    #pragma unroll
    for (int i = 0; i < 6; ++i) acc[i] = __float2half2_rn(0.0f);
    float dsum = 0.0f;

    #pragma unroll
    for (int k = 0; k < 4; ++k) {
        const int sp = q * 4 + k;
        const float2 j = jit2[sp * (SH * SW) + pix];
        const float posx = px + j.x * step;
        const float posy = py + j.y * step;

        const float thx = fast_tanh(tt * posx);
        const float thy = fast_tanh(tt * posy);
        const float ddx = tt * (1.0f - thx * thx) * inv_s;
        const float ddy = tt * (1.0f - thy * thy) * inv_s;
        const float det = ddx * ddy;

        float gx = (thx * inv_s + 1.0f) * (WI * 0.5f) - 0.5f;
        float gy = (thy * inv_s + 1.0f) * (HI * 0.5f) - 0.5f;
        gx = fminf(fmaxf(gx, 0.0f), (float)(WI - 1));
        gy = fminf(fmaxf(gy, 0.0f), (float)(HI - 1));

        const int xb = min((int)gx, WI - 2);
        const int yb = min((int)gy, HI - 2);
        const float fx = gx - (float)xb;
        const float fy = gy - (float)yb;

        const float w00 = (1.0f - fx) * (1.0f - fy) * det;
        const float w01 = fx * (1.0f - fy) * det;
        const float w10 = (1.0f - fx) * fy * det;
        const float w11 = fx * fy * det;
        dsum += det;

        const __half2 W00 = __float2half2_rn(w00);
        const __half2 W01 = __float2half2_rn(w01);
        const __half2 W10 = __float2half2_rn(w10);
        const __half2 W11 = __float2half2_rn(w11);

        const char* r0 = pk + (size_t)((uint)(yb * WI + xb)) * PXB;
        const char* r1 = r0 + WI * PXB;
        const uint4 a0  = *(const uint4*)(r0);             // px x,   row y0, ch0-7
        const uint2 a0h = *(const uint2*)(r0 + 16);        //                  ch8-11
        const uint4 b0  = *(const uint4*)(r0 + PXB);       // px x+1, row y0
        const uint2 b0h = *(const uint2*)(r0 + PXB + 16);
        const uint4 a1  = *(const uint4*)(r1);             // px x,   row y1
        const uint2 a1h = *(const uint2*)(r1 + 16);
        const uint4 b1  = *(const uint4*)(r1 + PXB);       // px x+1, row y1
        const uint2 b1h = *(const uint2*)(r1 + PXB + 16);

        const __half2* A0 = (const __half2*)&a0;
        const __half2* B0 = (const __half2*)&b0;
        const __half2* A1 = (const __half2*)&a1;
        const __half2* B1 = (const __half2*)&b1;
        #pragma unroll
        for (int i = 0; i < 4; ++i) {
            acc[i] = __hfma2(A0[i], W00, acc[i]);
            acc[i] = __hfma2(B0[i], W01, acc[i]);
            acc[i] = __hfma2(A1[i], W10, acc[i]);
            acc[i] = __hfma2(B1[i], W11, acc[i]);
        }
        const __half2* A0H = (const __half2*)&a0h;
        const __half2* B0H = (const __half2*)&b0h;
        const __half2* A1H = (const __half2*)&a1h;
        const __half2* B1H = (const __half2*)&b1h;
        #pragma unroll
        for (int i = 0; i < 2; ++i) {
            acc[4 + i] = __hfma2(A0H[i], W00, acc[4 + i]);
            acc[4 + i] = __hfma2(B0H[i], W01, acc[4 + i]);
            acc[4 + i] = __hfma2(A1H[i], W10, acc[4 + i]);
            acc[4 + i] = __hfma2(B1H[i], W11, acc[4 + i]);
        }
    }

    // Reduce the 4 spp quarters: butterfly over lane bits 4,5.
    #pragma unroll
    for (int m = 16; m <= 32; m <<= 1) {
        #pragma unroll
        for (int i = 0; i < 6; ++i) {
            const int t = __shfl_xor(__builtin_bit_cast(int, acc[i]), m);
            acc[i] = __hadd2(acc[i], __builtin_bit_cast(__half2, t));
        }
        dsum += __shfl_xor(dsum, m);
    }

    if (q == 0) {
        const float inv_d = 1.0f / dsum;
        #pragma unroll
        for (int p = 0; p < NPLANE; ++p) {
            const float v = (p & 1) ? __high2float(acc[p >> 1])
                                    : __low2float(acc[p >> 1]);
            out[(size_t)p * (SH * SW) + pix] = v * inv_d;
        }
    }
}

// ---- Fallback: R4 direct-gather kernel (used only if ws too small) --------
__global__ __launch_bounds__(256) void foveated_batch(
    const float* __restrict__ img,
    const float* __restrict__ t_ptr,
    const float* __restrict__ jitter,
    float* __restrict__ out)
{
    const int L   = (blockIdx.x & 7) * 512 + (blockIdx.x >> 3);
    const int sy  = L >> 4;
    const int sx0 = (L & 15) * 16;
    const int th  = threadIdx.x;
    const int sp  = th & 15;
    const int pxl = th >> 4;
    const int sx  = sx0 + pxl;

    const float step  = 2.0f / 256.0f;
    const float tt    = t_ptr[0];
    const float inv_s = __builtin_amdgcn_rcpf(fast_tanh(tt));

    const float2 j = ((const float2*)jitter)[sp * (SH * SW) + sy * SW + sx];
    const float posx = (-1.0f + sx * step) + j.x * step;
    const float posy = (-1.0f + sy * step) + j.y * step;

    const float thx = fast_tanh(tt * posx);
    const float thy = fast_tanh(tt * posy);
    const float ddx = tt * (1.0f - thx * thx) * inv_s;
    const float ddy = tt * (1.0f - thy * thy) * inv_s;
    const float det = ddx * ddy;

    float gx = (thx * inv_s + 1.0f) * (WI * 0.5f) - 0.5f;
    float gy = (thy * inv_s + 1.0f) * (HI * 0.5f) - 0.5f;
    gx = fminf(fmaxf(gx, 0.0f), (float)(WI - 1));
    gy = fminf(fmaxf(gy, 0.0f), (float)(HI - 1));

    const int xb = min((int)gx, WI - 2);
    const int yb = min((int)gy, HI - 2);
    const float fx = gx - (float)xb;
    const float fy = gy - (float)yb;

    const float w00 = (1.0f - fx) * (1.0f - fy) * det;
    const float w01 = fx * (1.0f - fy) * det;
    const float w10 = (1.0f - fx) * fy * det;
    const float w11 = fx * fy * det;

    const int i0 = yb * WI + xb;
    const int i1 = i0 + WI;
    const size_t plane = (size_t)HI * WI;

    float acc[BATCH][CH];
    #pragma unroll
    for (int b = 0; b < BATCH; ++b) {
        const float* __restrict__ pb = img + (size_t)(b * CH) * plane;
        #pragma unroll
        for (int c = 0; c < CH; ++c) {
            const float* __restrict__ p = pb + c * plane;
            const float2 a = *(const float2*)(p + i0);
            const float2 d = *(const float2*)(p + i1);
            acc[b][c] = a.x * w00 + a.y * w01 + d.x * w10 + d.y * w11;
        }
    }

    float dsum = det;
    #pragma unroll
    for (int m = 1; m < 16; m <<= 1) {
        #pragma unroll
        for (int b = 0; b < BATCH; ++b)
            #pragma unroll
            for (int c = 0; c < CH; ++c)
                acc[b][c] += __shfl_xor(acc[b][c], m);
        dsum += __shfl_xor(dsum, m);
    }

    if (sp == 0) {
        const float inv_d = 1.0f / dsum;
        const int pix = sy * SW + sx;
        #pragma unroll
        for (int b = 0; b < BATCH; ++b)
            #pragma unroll
            for (int c = 0; c < CH; ++c)
                out[(size_t)(b * CH + c) * (SH * SW) + pix] = acc[b][c] * inv_d;
    }
}

extern "C" void kernel_launch(void* const* d_in, const int* in_sizes, int n_in,
                              void* d_out, int out_size, void* d_ws, size_t ws_size,
                              hipStream_t stream) {
    const float* img    = (const float*)d_in[0];
    const float* t      = (const float*)d_in[1];
    const float* jitter = (const float*)d_in[2];
    float* out          = (float*)d_out;

    const size_t need = (size_t)HI * WI * PXB;   // 32 MB
    if (ws_size >= need) {
        char* pk = (char*)d_ws;
        hipLaunchKernelGGL(repack12, dim3(HI * WI / 256), dim3(256), 0, stream,
                           img, pk);
        hipLaunchKernelGGL(foveated_pk, dim3(1024), dim3(256), 0, stream,
                           pk, t, jitter, out);
    } else {
        hipLaunchKernelGGL(foveated_batch, dim3(4096), dim3(256), 0, stream,
                           img, t, jitter, out);
    }
}

// Round 8
// 114.396 us; speedup vs baseline: 1.0508x; 1.0508x over previous
//
#include <hip/hip_runtime.h>

// Problem constants (from reference)
#define SPP   16
#define SH    256
#define SW    256
#define HI    1024
#define WI    1024
#define CH    3
#define BATCH 4

// tanh via v_exp_f32; |arg| <= ~1.2 here, abs error ~1e-6 (threshold 1.7e-2).
__device__ __forceinline__ float fast_tanh(float x) {
    const float e = __expf(2.0f * x);
    return (e - 1.0f) * __builtin_amdgcn_rcpf(e + 1.0f);
}

// Thread = (sensor px, spp, batch-pair). Each thread computes its sample's
// geometry, then gathers SIX planes x 2 rows (batch-pair: planes bh*6..bh*6+5)
// with ALL 12 float2 loads hoisted into registers before any FMA (max MLP).
// Wave = 4 px x 16 spp (spp in lane bits 0-3) for one batch-pair; the 16-spp
// reduction is a 4-step __shfl_xor butterfly. Both halves compute dsum
// redundantly and write disjoint output planes — no cross-half traffic.
//
// 8192 blocks doubles wave count vs R4 (128 waves/CU queued) to hide gather
// latency; __launch_bounds__(256,6) keeps VGPR <= ~84 so 24 waves/CU fit.
//
// Border algebra: xb = min(floor(gx), W-2), fx = gx - xb (fx reaches 1.0 at
// the border) — identical to the reference's clamp.
__global__ __launch_bounds__(256, 6) void foveated_split(
    const float* __restrict__ img,
    const float* __restrict__ t_ptr,
    const float* __restrict__ jitter,
    float* __restrict__ out)
{
    // XCD slab swizzle: 1024 contiguous logical blocks per XCD. bh pairs are
    // adjacent in L, so both halves of a px-group share the XCD's L2 slab
    // (~1 MB img rows per XCD).
    const int L   = (blockIdx.x & 7) * 1024 + (blockIdx.x >> 3);
    const int bh  = L & 1;            // batch pair: 0 -> b{0,1}, 1 -> b{2,3}
    const int grp = L >> 1;           // 16-px sensor group, 0..4095

    const int th  = threadIdx.x;
    const int sp  = th & 15;          // spp (lane bits 0-3)
    const int lpx = (th >> 4) & 3;    // px within wave
    const int wv  = th >> 6;          // wave in block
    const int pix = grp * 16 + wv * 4 + lpx;
    const int sx  = pix & (SW - 1);
    const int sy  = pix >> 8;

    const float step  = 2.0f / 256.0f;
    const float tt    = t_ptr[0];
    const float inv_s = __builtin_amdgcn_rcpf(fast_tanh(tt));

    // ---- geometry (once per sample; batch-independent) ----
    const float2 j = ((const float2*)jitter)[sp * (SH * SW) + pix];
    const float posx = (-1.0f + sx * step) + j.x * step;
    const float posy = (-1.0f + sy * step) + j.y * step;

    const float thx = fast_tanh(tt * posx);
    const float thy = fast_tanh(tt * posy);
    const float ddx = tt * (1.0f - thx * thx) * inv_s;
    const float ddy = tt * (1.0f - thy * thy) * inv_s;
    const float det = ddx * ddy;

    float gx = (thx * inv_s + 1.0f) * (WI * 0.5f) - 0.5f;
    float gy = (thy * inv_s + 1.0f) * (HI * 0.5f) - 0.5f;
    gx = fminf(fmaxf(gx, 0.0f), (float)(WI - 1));
    gy = fminf(fmaxf(gy, 0.0f), (float)(HI - 1));

    const int xb = min((int)gx, WI - 2);
    const int yb = min((int)gy, HI - 2);
    const float fx = gx - (float)xb;
    const float fy = gy - (float)yb;

    const float w00 = (1.0f - fx) * (1.0f - fy) * det;
    const float w01 = fx * (1.0f - fy) * det;
    const float w10 = (1.0f - fx) * fy * det;
    const float w11 = fx * fy * det;

    const int i0 = yb * WI + xb;      // row yb, cols xb..xb+1
    const int i1 = i0 + WI;           // row yb+1
    const size_t plane = (size_t)HI * WI;

    // ---- gather: 6 planes x 2 rows, ALL loads issued before any FMA ----
    const float* __restrict__ pb = img + (size_t)(bh * 6) * plane;
    float2 r0[6], r1[6];
    #pragma unroll
    for (int p = 0; p < 6; ++p) {
        r0[p] = *(const float2*)(pb + p * plane + i0);
        r1[p] = *(const float2*)(pb + p * plane + i1);
    }

    float acc[6];
    #pragma unroll
    for (int p = 0; p < 6; ++p)
        acc[p] = r0[p].x * w00 + r0[p].y * w01 + r1[p].x * w10 + r1[p].y * w11;

    // ---- reduce 16 spp (butterfly over lane bits 0-3) ----
    float dsum = det;
    #pragma unroll
    for (int m = 1; m < 16; m <<= 1) {
        #pragma unroll
        for (int p = 0; p < 6; ++p)
            acc[p] += __shfl_xor(acc[p], m);
        dsum += __shfl_xor(dsum, m);
    }

    if (sp == 0) {
        const float inv_d = 1.0f / dsum;
        #pragma unroll
        for (int p = 0; p < 6; ++p)
            out[(size_t)(bh * 6 + p) * (SH * SW) + pix] = acc[p] * inv_d;
    }
}

extern "C" void kernel_launch(void* const* d_in, const int* in_sizes, int n_in,
                              void* d_out, int out_size, void* d_ws, size_t ws_size,
                              hipStream_t stream) {
    const float* img    = (const float*)d_in[0];
    const float* t      = (const float*)d_in[1];
    const float* jitter = (const float*)d_in[2];
    float* out          = (float*)d_out;

    // 4096 px-groups x 2 batch-pairs = 8192 blocks; 256 threads each.
    hipLaunchKernelGGL(foveated_split, dim3(8192), dim3(256), 0, stream,
                       img, t, jitter, out);
}

// Round 9
// 110.616 us; speedup vs baseline: 1.0868x; 1.0342x over previous
//
#include <hip/hip_runtime.h>
#include <hip/hip_fp16.h>

// Problem constants (from reference)
#define SPP   16
#define SH    256
#define SW    256
#define HI    1024
#define WI    1024
#define CH    3
#define BATCH 4

// 16-B gather with 8-B guaranteed alignment (gfx950 needs only dword align).
struct __attribute__((packed, aligned(8))) U4 { uint4 v; };

// tanh via v_exp_f32; |arg| <= ~1.2 here, abs error ~1e-6 (threshold 1.7e-2).
__device__ __forceinline__ float fast_tanh(float x) {
    const float e = __expf(2.0f * x);
    return (e - 1.0f) * __builtin_amdgcn_rcpf(e + 1.0f);
}

// ---- Pass 1: NCHW f32 -> per-batch NHWC4 fp16 (8 B/px), streaming ---------
__global__ __launch_bounds__(256) void repack_kernel(
    const float* __restrict__ img, __half* __restrict__ dst)
{
    const int tid = blockIdx.x * 256 + threadIdx.x;     // 0 .. 4*2^20-1
    const int b   = tid >> 20;
    const int pix = tid & (HI * WI - 1);
    const float* p = img + (size_t)b * (CH * HI * WI) + pix;
    union { __half2 h[2]; uint2 u; } v;
    v.h[0] = __floats2half2_rn(p[0], p[HI * WI]);
    v.h[1] = __floats2half2_rn(p[2 * HI * WI], 0.0f);
    *(uint2*)(dst + ((size_t)tid << 2)) = v.u;          // 8 B/lane, coalesced
}

// ---- Pass 2: spp-major narrow-wave gather, batch loop in thread -----------
// Thread = (sensor px, spp). Wave = 4 px x 16 spp -> gather footprint ~23 img
// px wide x ~7 rows = ~21 unique 64-B lines per gather instruction.
// One sample+batch = TWO 16-B loads (row-pair, all 3 channels, both texels).
// All 8 loads hoisted into registers (launch_bounds(256,6): VGPR cap ~85).
// Packed fp16 FMA; convert to f32 before the 16-spp butterfly (lane bits 0-3).
//
// Border algebra: xb = min(floor(gx), W-2), fx = gx - xb (reaches 1.0 at
// the border) — identical to the reference's clamp.
__global__ __launch_bounds__(256, 6) void foveated_nhwc_b(
    const __half* __restrict__ pk,
    const float* __restrict__ t_ptr,
    const float* __restrict__ jitter,
    float* __restrict__ out)
{
    // 4096 logical blocks of 16 sensor px; XCD slab swizzle (512 blocks =
    // 32 sensor rows per XCD).
    const int L   = (blockIdx.x & 7) * 512 + (blockIdx.x >> 3);
    const int th  = threadIdx.x;
    const int sp  = th & 15;          // spp (lane bits 0-3)
    const int lpx = th >> 4;          // px within block (0..15); 4 per wave
    const int pix = L * 16 + lpx;
    const int sx  = pix & (SW - 1);
    const int sy  = pix >> 8;

    const float step  = 2.0f / 256.0f;
    const float tt    = t_ptr[0];
    const float inv_s = __builtin_amdgcn_rcpf(fast_tanh(tt));

    // ---- geometry: once per sample, batch-independent ----
    const float2 j = ((const float2*)jitter)[sp * (SH * SW) + pix];
    const float posx = (-1.0f + sx * step) + j.x * step;
    const float posy = (-1.0f + sy * step) + j.y * step;

    const float thx = fast_tanh(tt * posx);
    const float thy = fast_tanh(tt * posy);
    const float ddx = tt * (1.0f - thx * thx) * inv_s;
    const float ddy = tt * (1.0f - thy * thy) * inv_s;
    const float det = ddx * ddy;

    float gx = (thx * inv_s + 1.0f) * (WI * 0.5f) - 0.5f;
    float gy = (thy * inv_s + 1.0f) * (HI * 0.5f) - 0.5f;
    gx = fminf(fmaxf(gx, 0.0f), (float)(WI - 1));
    gy = fminf(fmaxf(gy, 0.0f), (float)(HI - 1));

    const int xb = min((int)gx, WI - 2);
    const int yb = min((int)gy, HI - 2);
    const float fx = gx - (float)xb;
    const float fy = gy - (float)yb;

    const __half2 W00 = __float2half2_rn((1.0f - fx) * (1.0f - fy) * det);
    const __half2 W01 = __float2half2_rn(fx * (1.0f - fy) * det);
    const __half2 W10 = __float2half2_rn((1.0f - fx) * fy * det);
    const __half2 W11 = __float2half2_rn(fx * fy * det);

    const int i0 = (yb * WI + xb) << 2;   // halves; row yb, px xb..xb+1
    const int i1 = i0 + (WI << 2);        // row yb+1

    // ---- gather: 4 batches x 2 rows, ALL 8 loads issued up front ----
    uint4 r0[BATCH], r1[BATCH];
    #pragma unroll
    for (int b = 0; b < BATCH; ++b) {
        const __half* pb = pk + (size_t)b * (HI * WI * 4);
        r0[b] = ((const U4*)(pb + i0))->v;
        r1[b] = ((const U4*)(pb + i1))->v;
    }

    // ---- packed fp16 bilinear; f32 planes for the reduction ----
    float acc[BATCH * CH];
    #pragma unroll
    for (int b = 0; b < BATCH; ++b) {
        const __half2* a = (const __half2*)&r0[b];  // a0={c0,c1}px0 a1={c2,-}px0 a2,a3=px1
        const __half2* c = (const __half2*)&r1[b];
        __half2 sA = __hmul2(a[0], W00);            // {c0,c1}
        __half2 sB = __hmul2(a[1], W00);            // {c2,-}
        sA = __hfma2(a[2], W01, sA);
        sB = __hfma2(a[3], W01, sB);
        sA = __hfma2(c[0], W10, sA);
        sB = __hfma2(c[1], W10, sB);
        sA = __hfma2(c[2], W11, sA);
        sB = __hfma2(c[3], W11, sB);
        const float2 fA = __half22float2(sA);
        acc[b * CH + 0] = fA.x;
        acc[b * CH + 1] = fA.y;
        acc[b * CH + 2] = __low2float(sB);
    }

    // ---- reduce 16 spp: butterfly over lane bits 0-3, in f32 ----
    float dsum = det;
    #pragma unroll
    for (int m = 1; m < 16; m <<= 1) {
        #pragma unroll
        for (int p = 0; p < BATCH * CH; ++p)
            acc[p] += __shfl_xor(acc[p], m);
        dsum += __shfl_xor(dsum, m);
    }

    if (sp == 0) {
        const float inv_d = 1.0f / dsum;
        #pragma unroll
        for (int p = 0; p < BATCH * CH; ++p)
            out[(size_t)p * (SH * SW) + pix] = acc[p] * inv_d;
    }
}

// ---- Fallback: R7 direct-gather kernel (used only if ws too small) --------
__global__ __launch_bounds__(256, 6) void foveated_split(
    const float* __restrict__ img,
    const float* __restrict__ t_ptr,
    const float* __restrict__ jitter,
    float* __restrict__ out)
{
    const int L   = (blockIdx.x & 7) * 1024 + (blockIdx.x >> 3);
    const int bh  = L & 1;
    const int grp = L >> 1;

    const int th  = threadIdx.x;
    const int sp  = th & 15;
    const int lpx = (th >> 4) & 3;
    const int wv  = th >> 6;
    const int pix = grp * 16 + wv * 4 + lpx;
    const int sx  = pix & (SW - 1);
    const int sy  = pix >> 8;

    const float step  = 2.0f / 256.0f;
    const float tt    = t_ptr[0];
    const float inv_s = __builtin_amdgcn_rcpf(fast_tanh(tt));

    const float2 j = ((const float2*)jitter)[sp * (SH * SW) + pix];
    const float posx = (-1.0f + sx * step) + j.x * step;
    const float posy = (-1.0f + sy * step) + j.y * step;

    const float thx = fast_tanh(tt * posx);
    const float thy = fast_tanh(tt * posy);
    const float ddx = tt * (1.0f - thx * thx) * inv_s;
    const float ddy = tt * (1.0f - thy * thy) * inv_s;
    const float det = ddx * ddy;

    float gx = (thx * inv_s + 1.0f) * (WI * 0.5f) - 0.5f;
    float gy = (thy * inv_s + 1.0f) * (HI * 0.5f) - 0.5f;
    gx = fminf(fmaxf(gx, 0.0f), (float)(WI - 1));
    gy = fminf(fmaxf(gy, 0.0f), (float)(HI - 1));

    const int xb = min((int)gx, WI - 2);
    const int yb = min((int)gy, HI - 2);
    const float fx = gx - (float)xb;
    const float fy = gy - (float)yb;

    const float w00 = (1.0f - fx) * (1.0f - fy) * det;
    const float w01 = fx * (1.0f - fy) * det;
    const float w10 = (1.0f - fx) * fy * det;
    const float w11 = fx * fy * det;

    const int i0 = yb * WI + xb;
    const int i1 = i0 + WI;
    const size_t plane = (size_t)HI * WI;

    const float* __restrict__ pb = img + (size_t)(bh * 6) * plane;
    float2 r0[6], r1[6];
    #pragma unroll
    for (int p = 0; p < 6; ++p) {
        r0[p] = *(const float2*)(pb + p * plane + i0);
        r1[p] = *(const float2*)(pb + p * plane + i1);
    }

    float acc[6];
    #pragma unroll
    for (int p = 0; p < 6; ++p)
        acc[p] = r0[p].x * w00 + r0[p].y * w01 + r1[p].x * w10 + r1[p].y * w11;

    float dsum = det;
    #pragma unroll
    for (int m = 1; m < 16; m <<= 1) {
        #pragma unroll
        for (int p = 0; p < 6; ++p)
            acc[p] += __shfl_xor(acc[p], m);
        dsum += __shfl_xor(dsum, m);
    }

    if (sp == 0) {
        const float inv_d = 1.0f / dsum;
        #pragma unroll
        for (int p = 0; p < 6; ++p)
            out[(size_t)(bh * 6 + p) * (SH * SW) + pix] = acc[p] * inv_d;
    }
}

extern "C" void kernel_launch(void* const* d_in, const int* in_sizes, int n_in,
                              void* d_out, int out_size, void* d_ws, size_t ws_size,
                              hipStream_t stream) {
    const float* img    = (const float*)d_in[0];
    const float* t      = (const float*)d_in[1];
    const float* jitter = (const float*)d_in[2];
    float* out          = (float*)d_out;

    const size_t need = (size_t)BATCH * HI * WI * 4 * sizeof(__half); // 32 MB
    if (ws_size >= need) {
        __half* pkimg = (__half*)d_ws;
        hipLaunchKernelGGL(repack_kernel, dim3(BATCH * HI * WI / 256), dim3(256),
                           0, stream, img, pkimg);
        hipLaunchKernelGGL(foveated_nhwc_b, dim3(4096), dim3(256), 0, stream,
                           pkimg, t, jitter, out);
    } else {
        hipLaunchKernelGGL(foveated_split, dim3(8192), dim3(256), 0, stream,
                           img, t, jitter, out);
    }
}